// Round 12
// baseline (308.682 us; speedup 1.0000x reference)
//
#include <hip/hip_runtime.h>
#include <hip/hip_bf16.h>

// ---------- types ----------
typedef __attribute__((ext_vector_type(8))) short s16x8;   // 8 x bf16 (4 VGPR)
typedef __attribute__((ext_vector_type(4))) float f32x4;   // MFMA acc

#define B_SZ 64
#define T_SZ 2000
#define QD 1024
#define MD 512
#define AD 128
#define NF 32
#define KW 31
#define NTILE 63
#define ASTRIDE 1056   // Atile row stride in BYTES (264 words == 8 mod 32 banks)

// ---------- helpers ----------
__device__ __forceinline__ unsigned short f2bf(float f) {
    unsigned int u = __float_as_uint(f);
    unsigned int r = (u + 0x7FFFu + ((u >> 16) & 1u)) >> 16;  // RNE
    return (unsigned short)r;
}
__device__ __forceinline__ unsigned int pack2bf_manual(float a, float b) {
    return (unsigned int)f2bf(a) | ((unsigned int)f2bf(b) << 16);
}
__device__ __forceinline__ unsigned int pack2bf(float a, float b) {
    union { __hip_bfloat162 h; unsigned int u; } cv;
    cv.h = __float22bfloat162_rn(float2{a, b});
    return cv.u;
}
__device__ __forceinline__ float fast_tanh(float x) {
    float ax = fabsf(x);
    float e = __expf(2.0f * ax);
    float r = 1.0f - 2.0f * __builtin_amdgcn_rcpf(e + 1.0f);
    return x < 0.0f ? -r : r;
}

// ---------- kernel A: pq + weight packing (R6 verbatim) ----------
__global__ __launch_bounds__(512) void prep_kernel(
    const float* __restrict__ ahs, const float* __restrict__ Wq,
    const float* __restrict__ Wm, const float* __restrict__ Wl,
    float* __restrict__ pq, unsigned short* __restrict__ WB,
    unsigned short* __restrict__ WL) {
    const int blk = blockIdx.x, tid = threadIdx.x;
    if (blk < 64) {
        __shared__ float q_sm[QD];
        __shared__ float part[3][AD];
        ((float2*)q_sm)[tid] = ((const float2*)(ahs + blk * QD))[tid];
        __syncthreads();
        const int d = tid & 127, kh = tid >> 7;
        const int k0 = kh * 256;
        float a0 = 0, a1 = 0, a2 = 0, a3 = 0;
        #pragma unroll 4
        for (int k = k0; k < k0 + 256; k += 4) {
            a0 += q_sm[k]     * Wq[(k)     * AD + d];
            a1 += q_sm[k + 1] * Wq[(k + 1) * AD + d];
            a2 += q_sm[k + 2] * Wq[(k + 2) * AD + d];
            a3 += q_sm[k + 3] * Wq[(k + 3) * AD + d];
        }
        float s = (a0 + a1) + (a2 + a3);
        if (kh) part[kh - 1][d] = s;
        __syncthreads();
        if (tid < AD)
            pq[blk * AD + tid] =
                fast_tanh((s + part[0][tid]) + (part[1][tid] + part[2][tid]));
    } else if (blk < 80) {
        int cidx = (blk - 64) * 512 + tid;        // 0..8191 = (n,s,l)
        int n = cidx >> 10, s = (cidx >> 6) & 15, l = cidx & 63;
        int col = n * 16 + (l & 15);
        int krow = s * 32 + (l >> 4) * 8;
        float v[8];
        #pragma unroll
        for (int j = 0; j < 8; ++j) v[j] = Wm[(krow + j) * AD + col];
        uint4 pk;
        pk.x = pack2bf(v[0], v[1]); pk.y = pack2bf(v[2], v[3]);
        pk.z = pack2bf(v[4], v[5]); pk.w = pack2bf(v[6], v[7]);
        *(uint4*)(WB + cidx * 8) = pk;
    } else {
        int cidx = tid;                            // 0..511 = (n,l)
        int n = cidx >> 6, l = cidx & 63;
        int col = n * 16 + (l & 15);
        int krow = (l >> 4) * 8;
        float v[8];
        #pragma unroll
        for (int j = 0; j < 8; ++j) v[j] = Wl[(krow + j) * AD + col];
        uint4 pk;
        pk.x = pack2bf_manual(v[0], v[1]); pk.y = pack2bf_manual(v[2], v[3]);
        pk.z = pack2bf_manual(v[4], v[5]); pk.w = pack2bf_manual(v[6], v[7]);
        *(uint4*)(WL + cidx * 8) = pk;
    }
}

// ---------- kernel B: 2-tile pipelined blocks ----------
// grid (32, 64); block 256 (4 waves). Block gx owns tiles {2gx, 2gx+1};
// gx==31 owns only tail tile 62. Tile1's loads issue right after tile0's
// pm-MFMA (v[] dead there) and land after tile0's ctx phase.
__global__ __launch_bounds__(256, 4) void energy_kernel(
    const float* __restrict__ memory, const float* __restrict__ awcat,
    const float* __restrict__ Wconv, const float* __restrict__ Wv,
    const float* __restrict__ pq, const unsigned short* __restrict__ WB,
    const unsigned short* __restrict__ WL, float* __restrict__ wts,
    float* __restrict__ ctile, float* __restrict__ mloc,
    float* __restrict__ Stile) {
    const int gx = blockIdx.x;
    const int b = blockIdx.y;
    const int tid = threadIdx.x;
    const int tile0 = gx * 2;
    const int t0 = tile0 * 32;
    const bool two = (gx < 31);          // block-uniform

    __shared__ __align__(16) unsigned short Atile[32 * (ASTRIDE / 2)];
    __shared__ float aw_sm[2][64];
    __shared__ __align__(16) unsigned short conv_sm[32 * 40];
    __shared__ float e_part[32][4];
    __shared__ float p_sm[32];

    const int w = tid >> 6, l = tid & 63;
    const int lr = l & 15, lg = l >> 4;
    const int d0 = (2 * w + 0) * 16 + lr;
    const int d1 = (2 * w + 1) * 16 + lr;
    const float pqv0 = pq[b * AD + d0], pqv1 = pq[b * AD + d1];
    const float wvv0 = Wv[d0], wvv1 = Wv[d1];

    const s16x8* wbp = (const s16x8*)WB;
    const s16x8* wlp = (const s16x8*)WL;
    const int swz = (lr & 7) << 4;
    const int rbase0 = lr * ASTRIDE;
    const int rbase1 = (16 + lr) * ASTRIDE;
    const int inb = lg * 16;
    const char* Ac = (const char*)Atile;
    f32x4 zero4 = {0, 0, 0, 0};

    // ======== tile 0: stage ========
    float aw0 = 0.0f;
    if (tid < 128) {
        int c = tid >> 6, i = tid & 63;
        int tv = t0 - 15 + i;
        if (i < 63 && tv >= 0 && tv < T_SZ) aw0 = awcat[(b * 2 + c) * T_SZ + tv];
    }
    float4 v[16];
    {
        const float4* msrc = (const float4*)(memory + ((size_t)b * T_SZ + t0) * MD);
        if (two) {
            #pragma unroll
            for (int it = 0; it < 8; ++it) {
                int cid = it * 256 + tid;
                int r = cid >> 6, cc = cid & 63;
                v[2 * it]     = msrc[r * 128 + cc * 2];
                v[2 * it + 1] = msrc[r * 128 + cc * 2 + 1];
            }
        } else {
            #pragma unroll
            for (int it = 0; it < 8; ++it) {
                int cid = it * 256 + tid;
                int r = cid >> 6, cc = cid & 63;
                float4 z = {0, 0, 0, 0};
                bool ok = (t0 + r < T_SZ);
                v[2 * it]     = ok ? msrc[r * 128 + cc * 2]     : z;
                v[2 * it + 1] = ok ? msrc[r * 128 + cc * 2 + 1] : z;
            }
        }
    }
    #pragma unroll
    for (int it = 0; it < 8; ++it) {
        int cid = it * 256 + tid;
        int r = cid >> 6, cc = cid & 63;
        uint4 pk;
        pk.x = pack2bf(v[2 * it].x, v[2 * it].y);
        pk.y = pack2bf(v[2 * it].z, v[2 * it].w);
        pk.z = pack2bf(v[2 * it + 1].x, v[2 * it + 1].y);
        pk.w = pack2bf(v[2 * it + 1].z, v[2 * it + 1].w);
        *(uint4*)((char*)Atile + r * ASTRIDE + ((cc * 16) ^ ((r & 7) << 4))) = pk;
    }
    if (tid < 128) aw_sm[tid >> 6][tid & 63] = aw0;
    __syncthreads();

    // ======== tile 0: conv ========
    {
        int f = tid & 31, tq = tid >> 5;
        float acc[4] = {0, 0, 0, 0};
        for (int k = 0; k < KW; ++k) {
            #pragma unroll
            for (int c = 0; c < 2; ++c) {
                float wv = Wconv[(k * 2 + c) * NF + f];
                #pragma unroll
                for (int tt = 0; tt < 4; ++tt)
                    acc[tt] += wv * aw_sm[c][tq + tt * 8 + k];
            }
        }
        #pragma unroll
        for (int tt = 0; tt < 4; ++tt)
            conv_sm[(tq + tt * 8) * 40 + f] = f2bf(acc[tt]);
    }
    __syncthreads();

    // ======== tile 0: pm MFMA ========
    f32x4 p00 = zero4, p01 = zero4, p10 = zero4, p11 = zero4;
    #pragma unroll
    for (int s = 0; s < 16; ++s) {
        int j = (inb + s * 64) ^ swz;
        s16x8 a0 = *(const s16x8*)(Ac + rbase0 + j);
        s16x8 a1 = *(const s16x8*)(Ac + rbase1 + j);
        s16x8 b0 = wbp[((2 * w + 0) * 16 + s) * 64 + l];
        s16x8 b1 = wbp[((2 * w + 1) * 16 + s) * 64 + l];
        p00 = __builtin_amdgcn_mfma_f32_16x16x32_bf16(a0, b0, p00, 0, 0, 0);
        p01 = __builtin_amdgcn_mfma_f32_16x16x32_bf16(a0, b1, p01, 0, 0, 0);
        p10 = __builtin_amdgcn_mfma_f32_16x16x32_bf16(a1, b0, p10, 0, 0, 0);
        p11 = __builtin_amdgcn_mfma_f32_16x16x32_bf16(a1, b1, p11, 0, 0, 0);
    }

    // ======== issue tile 1 loads (v dead here; lands after ctx barrier) ====
    float aw1 = 0.0f;
    if (two) {
        const float4* msrc1 =
            (const float4*)(memory + ((size_t)b * T_SZ + t0 + 32) * MD);
        #pragma unroll
        for (int it = 0; it < 8; ++it) {
            int cid = it * 256 + tid;
            int r = cid >> 6, cc = cid & 63;
            v[2 * it]     = msrc1[r * 128 + cc * 2];
            v[2 * it + 1] = msrc1[r * 128 + cc * 2 + 1];
        }
        if (tid < 128) {
            int c = tid >> 6, i = tid & 63;
            if (i < 63) aw1 = awcat[(b * 2 + c) * T_SZ + (t0 + 17 + i)];
        }
    }

    // ======== tile 0: ploc MFMA + epilogue ========
    {
        s16x8 la0 = *(const s16x8*)((const char*)conv_sm + (lr * 80 + lg * 16));
        s16x8 la1 = *(const s16x8*)((const char*)conv_sm + ((16 + lr) * 80 + lg * 16));
        s16x8 lb0 = wlp[(2 * w + 0) * 64 + l];
        s16x8 lb1 = wlp[(2 * w + 1) * 64 + l];
        f32x4 q00 = __builtin_amdgcn_mfma_f32_16x16x32_bf16(la0, lb0, zero4, 0, 0, 0);
        f32x4 q01 = __builtin_amdgcn_mfma_f32_16x16x32_bf16(la0, lb1, zero4, 0, 0, 0);
        f32x4 q10 = __builtin_amdgcn_mfma_f32_16x16x32_bf16(la1, lb0, zero4, 0, 0, 0);
        f32x4 q11 = __builtin_amdgcn_mfma_f32_16x16x32_bf16(la1, lb1, zero4, 0, 0, 0);

        float vr[8];
        #pragma unroll
        for (int r = 0; r < 4; ++r) {
            vr[r]     = fast_tanh(pqv0 + fast_tanh(q00[r]) + fast_tanh(p00[r])) * wvv0
                      + fast_tanh(pqv1 + fast_tanh(q01[r]) + fast_tanh(p01[r])) * wvv1;
            vr[4 + r] = fast_tanh(pqv0 + fast_tanh(q10[r]) + fast_tanh(p10[r])) * wvv0
                      + fast_tanh(pqv1 + fast_tanh(q11[r]) + fast_tanh(p11[r])) * wvv1;
        }
        #pragma unroll
        for (int j = 0; j < 8; ++j) {
            float vv = vr[j];
            vv += __shfl_xor(vv, 1);
            vv += __shfl_xor(vv, 2);
            vv += __shfl_xor(vv, 4);
            vv += __shfl_xor(vv, 8);
            if (lr == 0) e_part[(j >> 2) * 16 + lg * 4 + (j & 3)][w] = vv;
        }
    }
    __syncthreads();

    // ======== tile 0: softmax ========
    if (tid < 32) {
        int t = t0 + tid;
        bool valid = t < T_SZ;
        float e = (e_part[tid][0] + e_part[tid][1]) + (e_part[tid][2] + e_part[tid][3]);
        float m = valid ? e : -3.4e38f;
        m = fmaxf(m, __shfl_xor(m, 1));
        m = fmaxf(m, __shfl_xor(m, 2));
        m = fmaxf(m, __shfl_xor(m, 4));
        m = fmaxf(m, __shfl_xor(m, 8));
        m = fmaxf(m, __shfl_xor(m, 16));
        float p = valid ? __expf(e - m) : 0.0f;
        p_sm[tid] = p;
        float S = p;
        S += __shfl_xor(S, 1);
        S += __shfl_xor(S, 2);
        S += __shfl_xor(S, 4);
        S += __shfl_xor(S, 8);
        S += __shfl_xor(S, 16);
        if (valid) wts[b * T_SZ + t] = p;
        if (tid == 0) { mloc[b * NTILE + tile0] = m; Stile[b * NTILE + tile0] = S; }
    }
    __syncthreads();

    // ======== tile 0: ctx partial ========
    {
        float c0 = 0.0f, c1 = 0.0f;
        const int boff = tid * 4;
        #pragma unroll
        for (int t = 0; t < 32; ++t) {
            float p = p_sm[t];
            unsigned int pk = *(const unsigned int*)(
                Ac + t * ASTRIDE + (boff ^ ((t & 7) << 4)));
            c0 += p * __uint_as_float(pk << 16);
            c1 += p * __uint_as_float(pk & 0xffff0000u);
        }
        float2 o; o.x = c0; o.y = c1;
        ((float2*)ctile)[((b * NTILE + tile0) << 8) + tid] = o;
    }

    if (!two) return;
    __syncthreads();   // Atile free for tile 1

    // ======== tile 1: write staged data ========
    #pragma unroll
    for (int it = 0; it < 8; ++it) {
        int cid = it * 256 + tid;
        int r = cid >> 6, cc = cid & 63;
        uint4 pk;
        pk.x = pack2bf(v[2 * it].x, v[2 * it].y);
        pk.y = pack2bf(v[2 * it].z, v[2 * it].w);
        pk.z = pack2bf(v[2 * it + 1].x, v[2 * it + 1].y);
        pk.w = pack2bf(v[2 * it + 1].z, v[2 * it + 1].w);
        *(uint4*)((char*)Atile + r * ASTRIDE + ((cc * 16) ^ ((r & 7) << 4))) = pk;
    }
    if (tid < 128) aw_sm[tid >> 6][tid & 63] = aw1;
    __syncthreads();

    // ======== tile 1: conv ========
    {
        int f = tid & 31, tq = tid >> 5;
        float acc[4] = {0, 0, 0, 0};
        for (int k = 0; k < KW; ++k) {
            #pragma unroll
            for (int c = 0; c < 2; ++c) {
                float wv = Wconv[(k * 2 + c) * NF + f];
                #pragma unroll
                for (int tt = 0; tt < 4; ++tt)
                    acc[tt] += wv * aw_sm[c][tq + tt * 8 + k];
            }
        }
        #pragma unroll
        for (int tt = 0; tt < 4; ++tt)
            conv_sm[(tq + tt * 8) * 40 + f] = f2bf(acc[tt]);
    }
    __syncthreads();

    // ======== tile 1: MFMA + epilogue ========
    {
        f32x4 s00 = zero4, s01 = zero4, s10 = zero4, s11 = zero4;
        #pragma unroll
        for (int s = 0; s < 16; ++s) {
            int j = (inb + s * 64) ^ swz;
            s16x8 a0 = *(const s16x8*)(Ac + rbase0 + j);
            s16x8 a1 = *(const s16x8*)(Ac + rbase1 + j);
            s16x8 b0 = wbp[((2 * w + 0) * 16 + s) * 64 + l];
            s16x8 b1 = wbp[((2 * w + 1) * 16 + s) * 64 + l];
            s00 = __builtin_amdgcn_mfma_f32_16x16x32_bf16(a0, b0, s00, 0, 0, 0);
            s01 = __builtin_amdgcn_mfma_f32_16x16x32_bf16(a0, b1, s01, 0, 0, 0);
            s10 = __builtin_amdgcn_mfma_f32_16x16x32_bf16(a1, b0, s10, 0, 0, 0);
            s11 = __builtin_amdgcn_mfma_f32_16x16x32_bf16(a1, b1, s11, 0, 0, 0);
        }
        s16x8 la0 = *(const s16x8*)((const char*)conv_sm + (lr * 80 + lg * 16));
        s16x8 la1 = *(const s16x8*)((const char*)conv_sm + ((16 + lr) * 80 + lg * 16));
        s16x8 lb0 = wlp[(2 * w + 0) * 64 + l];
        s16x8 lb1 = wlp[(2 * w + 1) * 64 + l];
        f32x4 q00 = __builtin_amdgcn_mfma_f32_16x16x32_bf16(la0, lb0, zero4, 0, 0, 0);
        f32x4 q01 = __builtin_amdgcn_mfma_f32_16x16x32_bf16(la0, lb1, zero4, 0, 0, 0);
        f32x4 q10 = __builtin_amdgcn_mfma_f32_16x16x32_bf16(la1, lb0, zero4, 0, 0, 0);
        f32x4 q11 = __builtin_amdgcn_mfma_f32_16x16x32_bf16(la1, lb1, zero4, 0, 0, 0);

        float vr[8];
        #pragma unroll
        for (int r = 0; r < 4; ++r) {
            vr[r]     = fast_tanh(pqv0 + fast_tanh(q00[r]) + fast_tanh(s00[r])) * wvv0
                      + fast_tanh(pqv1 + fast_tanh(q01[r]) + fast_tanh(s01[r])) * wvv1;
            vr[4 + r] = fast_tanh(pqv0 + fast_tanh(q10[r]) + fast_tanh(s10[r])) * wvv0
                      + fast_tanh(pqv1 + fast_tanh(q11[r]) + fast_tanh(s11[r])) * wvv1;
        }
        #pragma unroll
        for (int j = 0; j < 8; ++j) {
            float vv = vr[j];
            vv += __shfl_xor(vv, 1);
            vv += __shfl_xor(vv, 2);
            vv += __shfl_xor(vv, 4);
            vv += __shfl_xor(vv, 8);
            if (lr == 0) e_part[(j >> 2) * 16 + lg * 4 + (j & 3)][w] = vv;
        }
    }
    __syncthreads();

    // ======== tile 1: softmax ========
    if (tid < 32) {
        float e = (e_part[tid][0] + e_part[tid][1]) + (e_part[tid][2] + e_part[tid][3]);
        float m = e;
        m = fmaxf(m, __shfl_xor(m, 1));
        m = fmaxf(m, __shfl_xor(m, 2));
        m = fmaxf(m, __shfl_xor(m, 4));
        m = fmaxf(m, __shfl_xor(m, 8));
        m = fmaxf(m, __shfl_xor(m, 16));
        float p = __expf(e - m);
        p_sm[tid] = p;
        float S = p;
        S += __shfl_xor(S, 1);
        S += __shfl_xor(S, 2);
        S += __shfl_xor(S, 4);
        S += __shfl_xor(S, 8);
        S += __shfl_xor(S, 16);
        wts[b * T_SZ + t0 + 32 + tid] = p;
        if (tid == 0) {
            mloc[b * NTILE + tile0 + 1] = m;
            Stile[b * NTILE + tile0 + 1] = S;
        }
    }
    __syncthreads();

    // ======== tile 1: ctx partial ========
    {
        float c0 = 0.0f, c1 = 0.0f;
        const int boff = tid * 4;
        #pragma unroll
        for (int t = 0; t < 32; ++t) {
            float p = p_sm[t];
            unsigned int pk = *(const unsigned int*)(
                Ac + t * ASTRIDE + (boff ^ ((t & 7) << 4)));
            c0 += p * __uint_as_float(pk << 16);
            c1 += p * __uint_as_float(pk & 0xffff0000u);
        }
        float2 o; o.x = c0; o.y = c1;
        ((float2*)ctile)[((b * NTILE + tile0 + 1) << 8) + tid] = o;
    }
}

// ---------- kernel C: finalize (R6 verbatim) ----------
__global__ __launch_bounds__(256) void finalize_kernel(
    const float* __restrict__ mloc, const float* __restrict__ Stile,
    const float* __restrict__ ctile, float* __restrict__ wts,
    float* __restrict__ ctx) {
    const int b = blockIdx.x, h = blockIdx.y, tid = threadIdx.x;
    __shared__ float sc_sm[NTILE + 1];
    if (tid < 64) {
        float m = (tid < NTILE) ? mloc[b * NTILE + tid] : -3.4e38f;
        float s = (tid < NTILE) ? Stile[b * NTILE + tid] : 0.0f;
        float M = m;
        M = fmaxf(M, __shfl_xor(M, 1));  M = fmaxf(M, __shfl_xor(M, 2));
        M = fmaxf(M, __shfl_xor(M, 4));  M = fmaxf(M, __shfl_xor(M, 8));
        M = fmaxf(M, __shfl_xor(M, 16)); M = fmaxf(M, __shfl_xor(M, 32));
        float e = __expf(m - M);
        float z = e * s;
        z += __shfl_xor(z, 1);  z += __shfl_xor(z, 2);
        z += __shfl_xor(z, 4);  z += __shfl_xor(z, 8);
        z += __shfl_xor(z, 16); z += __shfl_xor(z, 32);
        if (tid < NTILE) sc_sm[tid] = e / z;
    }
    __syncthreads();

    if (h == 0) {
        #pragma unroll
        for (int i = 0; i < 8; ++i) {
            int idx = tid + i * 256;
            if (idx < T_SZ) wts[b * T_SZ + idx] *= sc_sm[idx >> 5];
        }
    }

    float a = 0.0f;
    const float* cb = ctile + ((size_t)b * NTILE << 9) + h * 256 + tid;
    #pragma unroll 7
    for (int tl = 0; tl < NTILE; ++tl) a += sc_sm[tl] * cb[(size_t)tl << 9];
    ctx[b * MD + h * 256 + tid] = a;
}

// ---------- launch ----------
extern "C" void kernel_launch(void* const* d_in, const int* in_sizes, int n_in,
                              void* d_out, int out_size, void* d_ws, size_t ws_size,
                              hipStream_t stream) {
    const float* ahs    = (const float*)d_in[0];
    const float* memory = (const float*)d_in[1];
    const float* awcat  = (const float*)d_in[2];
    const float* Wq     = (const float*)d_in[3];
    const float* Wm     = (const float*)d_in[4];
    const float* Wv     = (const float*)d_in[5];
    const float* Wconv  = (const float*)d_in[6];
    const float* Wl     = (const float*)d_in[7];

    float* out = (float*)d_out;
    float* ctx = out;                 // [64][512]
    float* wts = out + B_SZ * MD;     // [64][2000]

    char* ws = (char*)d_ws;
    float* pq             = (float*)(ws);                    // 32 KB
    unsigned short* WB    = (unsigned short*)(ws + 32768);   // 128 KB
    unsigned short* WL    = (unsigned short*)(ws + 163840);  // 8 KB
    float* mloc           = (float*)(ws + 172032);           // 15.75 KB
    float* Stile          = (float*)(ws + 188160);           // 15.75 KB
    float* ctile          = (float*)(ws + 204800);           // 8.25 MB

    prep_kernel<<<81, 512, 0, stream>>>(ahs, Wq, Wm, Wl, pq, WB, WL);
    energy_kernel<<<dim3(32, B_SZ), 256, 0, stream>>>(
        memory, awcat, Wconv, Wv, pq, WB, WL, wts, ctile, mloc, Stile);
    finalize_kernel<<<dim3(B_SZ, 2), 256, 0, stream>>>(mloc, Stile, ctile, wts, ctx);
}

// Round 13
// 122.598 us; speedup vs baseline: 2.5178x; 2.5178x over previous
//
#include <hip/hip_runtime.h>
#include <hip/hip_bf16.h>

// ---------- types ----------
typedef __attribute__((ext_vector_type(8))) short s16x8;   // 8 x bf16 (4 VGPR)
typedef __attribute__((ext_vector_type(4))) float f32x4;   // MFMA acc

#define B_SZ 64
#define T_SZ 2000
#define QD 1024
#define MD 512
#define AD 128
#define NF 32
#define KW 31
#define NTILE 63
#define ASTRIDE 1056   // Atile row stride in BYTES (264 words == 8 mod 32 banks)
#define ABUF (32 * (ASTRIDE / 2))   // shorts per buffer

// lgkmcnt-only barrier: does NOT drain vmcnt -> global prefetch survives
#define LGKM_BAR() do { \
    asm volatile("s_waitcnt lgkmcnt(0)" ::: "memory"); \
    __builtin_amdgcn_s_barrier(); \
} while (0)

// ---------- helpers ----------
__device__ __forceinline__ unsigned short f2bf(float f) {
    unsigned int u = __float_as_uint(f);
    unsigned int r = (u + 0x7FFFu + ((u >> 16) & 1u)) >> 16;  // RNE
    return (unsigned short)r;
}
__device__ __forceinline__ unsigned int pack2bf_manual(float a, float b) {
    return (unsigned int)f2bf(a) | ((unsigned int)f2bf(b) << 16);
}
__device__ __forceinline__ unsigned int pack2bf(float a, float b) {
    union { __hip_bfloat162 h; unsigned int u; } cv;
    cv.h = __float22bfloat162_rn(float2{a, b});
    return cv.u;
}
__device__ __forceinline__ float fast_tanh(float x) {
    float ax = fabsf(x);
    float e = __expf(2.0f * ax);
    float r = 1.0f - 2.0f * __builtin_amdgcn_rcpf(e + 1.0f);
    return x < 0.0f ? -r : r;
}

// ---------- kernel A: pq + weight packing (R6 verbatim) ----------
__global__ __launch_bounds__(512) void prep_kernel(
    const float* __restrict__ ahs, const float* __restrict__ Wq,
    const float* __restrict__ Wm, const float* __restrict__ Wl,
    float* __restrict__ pq, unsigned short* __restrict__ WB,
    unsigned short* __restrict__ WL) {
    const int blk = blockIdx.x, tid = threadIdx.x;
    if (blk < 64) {
        __shared__ float q_sm[QD];
        __shared__ float part[3][AD];
        ((float2*)q_sm)[tid] = ((const float2*)(ahs + blk * QD))[tid];
        __syncthreads();
        const int d = tid & 127, kh = tid >> 7;
        const int k0 = kh * 256;
        float a0 = 0, a1 = 0, a2 = 0, a3 = 0;
        #pragma unroll 4
        for (int k = k0; k < k0 + 256; k += 4) {
            a0 += q_sm[k]     * Wq[(k)     * AD + d];
            a1 += q_sm[k + 1] * Wq[(k + 1) * AD + d];
            a2 += q_sm[k + 2] * Wq[(k + 2) * AD + d];
            a3 += q_sm[k + 3] * Wq[(k + 3) * AD + d];
        }
        float s = (a0 + a1) + (a2 + a3);
        if (kh) part[kh - 1][d] = s;
        __syncthreads();
        if (tid < AD)
            pq[blk * AD + tid] =
                fast_tanh((s + part[0][tid]) + (part[1][tid] + part[2][tid]));
    } else if (blk < 80) {
        int cidx = (blk - 64) * 512 + tid;        // 0..8191 = (n,s,l)
        int n = cidx >> 10, s = (cidx >> 6) & 15, l = cidx & 63;
        int col = n * 16 + (l & 15);
        int krow = s * 32 + (l >> 4) * 8;
        float v[8];
        #pragma unroll
        for (int j = 0; j < 8; ++j) v[j] = Wm[(krow + j) * AD + col];
        uint4 pk;
        pk.x = pack2bf(v[0], v[1]); pk.y = pack2bf(v[2], v[3]);
        pk.z = pack2bf(v[4], v[5]); pk.w = pack2bf(v[6], v[7]);
        *(uint4*)(WB + cidx * 8) = pk;
    } else {
        int cidx = tid;                            // 0..511 = (n,l)
        int n = cidx >> 6, l = cidx & 63;
        int col = n * 16 + (l & 15);
        int krow = (l >> 4) * 8;
        float v[8];
        #pragma unroll
        for (int j = 0; j < 8; ++j) v[j] = Wl[(krow + j) * AD + col];
        uint4 pk;
        pk.x = pack2bf_manual(v[0], v[1]); pk.y = pack2bf_manual(v[2], v[3]);
        pk.z = pack2bf_manual(v[4], v[5]); pk.w = pack2bf_manual(v[6], v[7]);
        *(uint4*)(WL + cidx * 8) = pk;
    }
}

// ---------- kernel B: persistent pipelined blocks, 1 block/CU ----------
// grid (4, 64); block 512 (8 waves, wave = one 16-d chunk, B-frags in VGPRs).
// 16 tiles per block (gx=3: 15), LDS double-buffered Atile, lgkm-only barriers.
__global__ __launch_bounds__(512, 2) void energy_kernel(
    const float* __restrict__ memory, const float* __restrict__ awcat,
    const float* __restrict__ Wconv, const float* __restrict__ Wv,
    const float* __restrict__ pq, const unsigned short* __restrict__ WB,
    const unsigned short* __restrict__ WL, float* __restrict__ wts,
    float* __restrict__ ctile, float* __restrict__ mloc,
    float* __restrict__ Stile) {
    const int gx = blockIdx.x;
    const int b = blockIdx.y;
    const int tid = threadIdx.x;
    const int base = gx * 16;
    const int NT = (base + 16 <= NTILE) ? 16 : (NTILE - base);

    __shared__ __align__(16) unsigned short Atile[2 * ABUF];   // 66 KB
    __shared__ float wconv_sm[KW * 2 * NF];                    // 7.75 KB
    __shared__ float awc[2][2][64];                            // 1 KB
    __shared__ __align__(16) unsigned short conv_sm[32 * 40];  // 2.5 KB
    __shared__ float e_part[32][8];                            // 1 KB
    __shared__ float e_sm[32];
    __shared__ float p_sm[32];

    const int w = tid >> 6, l = tid & 63;
    const int lr = l & 15, lg = l >> 4;
    const int d = w * 16 + lr;
    const float pqv = pq[b * AD + d];
    const float wvv = Wv[d];
    const int swz = (lr & 7) << 4;
    const f32x4 zero4 = {0, 0, 0, 0};

    // B-fragments for this wave's chunk: 16 x 16B = 64 VGPR, loaded ONCE
    const s16x8* wbp = (const s16x8*)WB;
    s16x8 breg[16];
    #pragma unroll
    for (int s = 0; s < 16; ++s) breg[s] = wbp[(w * 16 + s) * 64 + l];
    s16x8 lb = ((const s16x8*)WL)[w * 64 + l];

    // Wconv -> LDS (1984 floats = 496 float4)
    if (tid < 496) ((float4*)wconv_sm)[tid] = ((const float4*)Wconv)[tid];

    // ---- prologue: stage tile `base` into buffer 0 ----
    {
        const int t0 = base * 32;
        float aw0 = 0.0f;
        if (tid < 128) {
            int c = tid >> 6, i = tid & 63;
            int tv = t0 - 15 + i;
            if (i < 63 && tv >= 0 && tv < T_SZ) aw0 = awcat[(b * 2 + c) * T_SZ + tv];
        }
        const float4* msrc = (const float4*)(memory + ((size_t)b * T_SZ + t0) * MD);
        float4 v0[8];
        #pragma unroll
        for (int it = 0; it < 4; ++it) {
            int cid = it * 512 + tid, r = cid >> 6, cc = cid & 63;
            v0[2 * it]     = msrc[r * 128 + cc * 2];
            v0[2 * it + 1] = msrc[r * 128 + cc * 2 + 1];
        }
        #pragma unroll
        for (int it = 0; it < 4; ++it) {
            int cid = it * 512 + tid, r = cid >> 6, cc = cid & 63;
            uint4 pk;
            pk.x = pack2bf(v0[2 * it].x, v0[2 * it].y);
            pk.y = pack2bf(v0[2 * it].z, v0[2 * it].w);
            pk.z = pack2bf(v0[2 * it + 1].x, v0[2 * it + 1].y);
            pk.w = pack2bf(v0[2 * it + 1].z, v0[2 * it + 1].w);
            *(uint4*)((char*)Atile + r * ASTRIDE + ((cc * 16) ^ ((r & 7) << 4))) = pk;
        }
        if (tid < 128) awc[0][tid >> 6][tid & 63] = aw0;
    }
    __syncthreads();   // prologue only: full barrier is fine here

    float4 v[8];
    float aw1 = 0.0f;

    for (int j = 0; j < NT; ++j) {
        const int tile = base + j;
        const int t0 = tile * 32;
        const int cur = j & 1;
        const bool hasNext = (j + 1 < NT);

        // ---- issue next tile's loads (stay in flight through compute) ----
        if (hasNext) {
            const int tn0 = t0 + 32;
            aw1 = 0.0f;
            if (tid < 128) {
                int c = tid >> 6, i = tid & 63;
                int tv = tn0 - 15 + i;
                if (i < 63 && tv >= 0 && tv < T_SZ)
                    aw1 = awcat[(b * 2 + c) * T_SZ + tv];
            }
            const float4* msrc =
                (const float4*)(memory + ((size_t)b * T_SZ + tn0) * MD);
            if (tn0 + 32 <= T_SZ) {
                #pragma unroll
                for (int it = 0; it < 4; ++it) {
                    int cid = it * 512 + tid, r = cid >> 6, cc = cid & 63;
                    v[2 * it]     = msrc[r * 128 + cc * 2];
                    v[2 * it + 1] = msrc[r * 128 + cc * 2 + 1];
                }
            } else {
                #pragma unroll
                for (int it = 0; it < 4; ++it) {
                    int cid = it * 512 + tid, r = cid >> 6, cc = cid & 63;
                    float4 z = {0, 0, 0, 0};
                    bool ok = (tn0 + r < T_SZ);
                    v[2 * it]     = ok ? msrc[r * 128 + cc * 2]     : z;
                    v[2 * it + 1] = ok ? msrc[r * 128 + cc * 2 + 1] : z;
                }
            }
        }

        // ---- conv (LDS-only inputs) ----
        {
            int f = tid & 31, tq = tid >> 5;
            float a0 = 0, a1 = 0;
            for (int k = 0; k < KW; ++k) {
                #pragma unroll
                for (int c = 0; c < 2; ++c) {
                    float wv = wconv_sm[(k * 2 + c) * NF + f];
                    a0 += wv * awc[cur][c][tq + k];
                    a1 += wv * awc[cur][c][tq + 16 + k];
                }
            }
            conv_sm[(tq)      * 40 + f] = f2bf(a0);
            conv_sm[(tq + 16) * 40 + f] = f2bf(a1);
        }
        LGKM_BAR();

        // ---- MFMA: wave w, chunk w, both 16-row halves ----
        const char* Ac = (const char*)(Atile + cur * ABUF);
        f32x4 p00 = zero4, p10 = zero4;
        #pragma unroll
        for (int s = 0; s < 16; ++s) {
            int jj = (lg * 16 + s * 64) ^ swz;
            s16x8 a0 = *(const s16x8*)(Ac + lr * ASTRIDE + jj);
            s16x8 a1 = *(const s16x8*)(Ac + (16 + lr) * ASTRIDE + jj);
            p00 = __builtin_amdgcn_mfma_f32_16x16x32_bf16(a0, breg[s], p00, 0, 0, 0);
            p10 = __builtin_amdgcn_mfma_f32_16x16x32_bf16(a1, breg[s], p10, 0, 0, 0);
        }
        s16x8 la0 = *(const s16x8*)((const char*)conv_sm + (lr * 80 + lg * 16));
        s16x8 la1 = *(const s16x8*)((const char*)conv_sm + ((16 + lr) * 80 + lg * 16));
        f32x4 q00 = __builtin_amdgcn_mfma_f32_16x16x32_bf16(la0, lb, zero4, 0, 0, 0);
        f32x4 q10 = __builtin_amdgcn_mfma_f32_16x16x32_bf16(la1, lb, zero4, 0, 0, 0);

        // ---- epilogue: per-wave 16-d partials ----
        #pragma unroll
        for (int r = 0; r < 4; ++r) {
            float v0 = fast_tanh(pqv + fast_tanh(q00[r]) + fast_tanh(p00[r])) * wvv;
            v0 += __shfl_xor(v0, 1);
            v0 += __shfl_xor(v0, 2);
            v0 += __shfl_xor(v0, 4);
            v0 += __shfl_xor(v0, 8);
            if (lr == 0) e_part[lg * 4 + r][w] = v0;
            float v1 = fast_tanh(pqv + fast_tanh(q10[r]) + fast_tanh(p10[r])) * wvv;
            v1 += __shfl_xor(v1, 1);
            v1 += __shfl_xor(v1, 2);
            v1 += __shfl_xor(v1, 4);
            v1 += __shfl_xor(v1, 8);
            if (lr == 0) e_part[16 + lg * 4 + r][w] = v1;
        }
        LGKM_BAR();

        // ---- cross-wave reduce ----
        if (tid < 256) {
            int t = tid >> 3, g = tid & 7;
            float vv = e_part[t][g];
            vv += __shfl_xor(vv, 1);
            vv += __shfl_xor(vv, 2);
            vv += __shfl_xor(vv, 4);
            if (g == 0) e_sm[t] = (t0 + t < T_SZ) ? vv : -3.4e38f;
        }
        LGKM_BAR();

        // ---- softmax numerators (wave 0) ----
        if (tid < 32) {
            int t = t0 + tid;
            bool valid = t < T_SZ;
            float e = e_sm[tid];
            float m = e;
            m = fmaxf(m, __shfl_xor(m, 1));
            m = fmaxf(m, __shfl_xor(m, 2));
            m = fmaxf(m, __shfl_xor(m, 4));
            m = fmaxf(m, __shfl_xor(m, 8));
            m = fmaxf(m, __shfl_xor(m, 16));
            float p = valid ? __expf(e - m) : 0.0f;
            p_sm[tid] = p;
            float S = p;
            S += __shfl_xor(S, 1);
            S += __shfl_xor(S, 2);
            S += __shfl_xor(S, 4);
            S += __shfl_xor(S, 8);
            S += __shfl_xor(S, 16);
            if (valid) wts[b * T_SZ + t] = p;
            if (tid == 0) { mloc[b * NTILE + tile] = m; Stile[b * NTILE + tile] = S; }
        }
        LGKM_BAR();

        // ---- ctx partial: thread owns ONE d = tid ----
        {
            float c = 0.0f;
            const int boff = 2 * tid;
            #pragma unroll
            for (int t = 0; t < 32; ++t) {
                unsigned short us = *(const unsigned short*)(
                    Ac + t * ASTRIDE + (boff ^ ((t & 7) << 4)));
                c += p_sm[t] * __uint_as_float(((unsigned int)us) << 16);
            }
            ctile[(((size_t)b * NTILE + tile) << 9) + tid] = c;
        }

        // ---- write next tile into other buffer (the only vmcnt wait) ----
        if (hasNext) {
            char* An = (char*)(Atile + (cur ^ 1) * ABUF);
            #pragma unroll
            for (int it = 0; it < 4; ++it) {
                int cid = it * 512 + tid, r = cid >> 6, cc = cid & 63;
                uint4 pk;
                pk.x = pack2bf(v[2 * it].x, v[2 * it].y);
                pk.y = pack2bf(v[2 * it].z, v[2 * it].w);
                pk.z = pack2bf(v[2 * it + 1].x, v[2 * it + 1].y);
                pk.w = pack2bf(v[2 * it + 1].z, v[2 * it + 1].w);
                *(uint4*)(An + r * ASTRIDE + ((cc * 16) ^ ((r & 7) << 4))) = pk;
            }
            if (tid < 128) awc[cur ^ 1][tid >> 6][tid & 63] = aw1;
        }
        LGKM_BAR();
    }
}

// ---------- kernel C: finalize (R6 verbatim) ----------
__global__ __launch_bounds__(256) void finalize_kernel(
    const float* __restrict__ mloc, const float* __restrict__ Stile,
    const float* __restrict__ ctile, float* __restrict__ wts,
    float* __restrict__ ctx) {
    const int b = blockIdx.x, h = blockIdx.y, tid = threadIdx.x;
    __shared__ float sc_sm[NTILE + 1];
    if (tid < 64) {
        float m = (tid < NTILE) ? mloc[b * NTILE + tid] : -3.4e38f;
        float s = (tid < NTILE) ? Stile[b * NTILE + tid] : 0.0f;
        float M = m;
        M = fmaxf(M, __shfl_xor(M, 1));  M = fmaxf(M, __shfl_xor(M, 2));
        M = fmaxf(M, __shfl_xor(M, 4));  M = fmaxf(M, __shfl_xor(M, 8));
        M = fmaxf(M, __shfl_xor(M, 16)); M = fmaxf(M, __shfl_xor(M, 32));
        float e = __expf(m - M);
        float z = e * s;
        z += __shfl_xor(z, 1);  z += __shfl_xor(z, 2);
        z += __shfl_xor(z, 4);  z += __shfl_xor(z, 8);
        z += __shfl_xor(z, 16); z += __shfl_xor(z, 32);
        if (tid < NTILE) sc_sm[tid] = e / z;
    }
    __syncthreads();

    if (h == 0) {
        #pragma unroll
        for (int i = 0; i < 8; ++i) {
            int idx = tid + i * 256;
            if (idx < T_SZ) wts[b * T_SZ + idx] *= sc_sm[idx >> 5];
        }
    }

    float a = 0.0f;
    const float* cb = ctile + ((size_t)b * NTILE << 9) + h * 256 + tid;
    #pragma unroll 7
    for (int tl = 0; tl < NTILE; ++tl) a += sc_sm[tl] * cb[(size_t)tl << 9];
    ctx[b * MD + h * 256 + tid] = a;
}

// ---------- launch ----------
extern "C" void kernel_launch(void* const* d_in, const int* in_sizes, int n_in,
                              void* d_out, int out_size, void* d_ws, size_t ws_size,
                              hipStream_t stream) {
    const float* ahs    = (const float*)d_in[0];
    const float* memory = (const float*)d_in[1];
    const float* awcat  = (const float*)d_in[2];
    const float* Wq     = (const float*)d_in[3];
    const float* Wm     = (const float*)d_in[4];
    const float* Wv     = (const float*)d_in[5];
    const float* Wconv  = (const float*)d_in[6];
    const float* Wl     = (const float*)d_in[7];

    float* out = (float*)d_out;
    float* ctx = out;                 // [64][512]
    float* wts = out + B_SZ * MD;     // [64][2000]

    char* ws = (char*)d_ws;
    float* pq             = (float*)(ws);                    // 32 KB
    unsigned short* WB    = (unsigned short*)(ws + 32768);   // 128 KB
    unsigned short* WL    = (unsigned short*)(ws + 163840);  // 8 KB
    float* mloc           = (float*)(ws + 172032);           // 15.75 KB
    float* Stile          = (float*)(ws + 188160);           // 15.75 KB
    float* ctile          = (float*)(ws + 204800);           // 8.25 MB

    prep_kernel<<<81, 512, 0, stream>>>(ahs, Wq, Wm, Wl, pq, WB, WL);
    energy_kernel<<<dim3(4, B_SZ), 512, 0, stream>>>(
        memory, awcat, Wconv, Wv, pq, WB, WL, wts, ctile, mloc, Stile);
    finalize_kernel<<<dim3(B_SZ, 2), 256, 0, stream>>>(mloc, Stile, ctile, wts, ctx);
}

// Round 14
// 89.833 us; speedup vs baseline: 3.4362x; 1.3647x over previous
//
#include <hip/hip_runtime.h>
#include <hip/hip_bf16.h>

// ---------- types ----------
typedef __attribute__((ext_vector_type(8))) short s16x8;   // 8 x bf16 (4 VGPR)
typedef __attribute__((ext_vector_type(4))) float f32x4;   // MFMA acc

#define B_SZ 64
#define T_SZ 2000
#define QD 1024
#define MD 512
#define AD 128
#define NF 32
#define KW 31
#define NTILE 63
#define ASTRIDE 1056   // Atile row stride in BYTES (264 words == 8 mod 32 banks)

// ---------- helpers ----------
__device__ __forceinline__ unsigned short f2bf(float f) {
    unsigned int u = __float_as_uint(f);
    unsigned int r = (u + 0x7FFFu + ((u >> 16) & 1u)) >> 16;  // RNE
    return (unsigned short)r;
}
__device__ __forceinline__ unsigned int pack2bf_manual(float a, float b) {
    return (unsigned int)f2bf(a) | ((unsigned int)f2bf(b) << 16);
}
__device__ __forceinline__ unsigned int pack2bf(float a, float b) {
    union { __hip_bfloat162 h; unsigned int u; } cv;
    cv.h = __float22bfloat162_rn(float2{a, b});
    return cv.u;
}
__device__ __forceinline__ float fast_tanh(float x) {
    float ax = fabsf(x);
    float e = __expf(2.0f * ax);
    float r = 1.0f - 2.0f * __builtin_amdgcn_rcpf(e + 1.0f);
    return x < 0.0f ? -r : r;
}

// ---------- kernel A: pq + weight packing ----------
// blocks 0..63: pq (512 thr, 4-way k-split); 64..79: WB pack; 80: WL pack
__global__ __launch_bounds__(512) void prep_kernel(
    const float* __restrict__ ahs, const float* __restrict__ Wq,
    const float* __restrict__ Wm, const float* __restrict__ Wl,
    float* __restrict__ pq, unsigned short* __restrict__ WB,
    unsigned short* __restrict__ WL) {
    const int blk = blockIdx.x, tid = threadIdx.x;
    if (blk < 64) {
        __shared__ float q_sm[QD];
        __shared__ float part[3][AD];
        ((float2*)q_sm)[tid] = ((const float2*)(ahs + blk * QD))[tid];
        __syncthreads();
        const int d = tid & 127, kh = tid >> 7;
        const int k0 = kh * 256;
        float a0 = 0, a1 = 0, a2 = 0, a3 = 0;
        #pragma unroll 4
        for (int k = k0; k < k0 + 256; k += 4) {
            a0 += q_sm[k]     * Wq[(k)     * AD + d];
            a1 += q_sm[k + 1] * Wq[(k + 1) * AD + d];
            a2 += q_sm[k + 2] * Wq[(k + 2) * AD + d];
            a3 += q_sm[k + 3] * Wq[(k + 3) * AD + d];
        }
        float s = (a0 + a1) + (a2 + a3);
        if (kh) part[kh - 1][d] = s;
        __syncthreads();
        if (tid < AD)
            pq[blk * AD + tid] =
                fast_tanh((s + part[0][tid]) + (part[1][tid] + part[2][tid]));
    } else if (blk < 80) {
        int cidx = (blk - 64) * 512 + tid;        // 0..8191 = (n,s,l)
        int n = cidx >> 10, s = (cidx >> 6) & 15, l = cidx & 63;
        int col = n * 16 + (l & 15);
        int krow = s * 32 + (l >> 4) * 8;
        float v[8];
        #pragma unroll
        for (int j = 0; j < 8; ++j) v[j] = Wm[(krow + j) * AD + col];
        uint4 pk;
        pk.x = pack2bf(v[0], v[1]); pk.y = pack2bf(v[2], v[3]);
        pk.z = pack2bf(v[4], v[5]); pk.w = pack2bf(v[6], v[7]);
        *(uint4*)(WB + cidx * 8) = pk;
    } else {
        int cidx = tid;                            // 0..511 = (n,l)
        int n = cidx >> 6, l = cidx & 63;
        int col = n * 16 + (l & 15);
        int krow = (l >> 4) * 8;
        float v[8];
        #pragma unroll
        for (int j = 0; j < 8; ++j) v[j] = Wl[(krow + j) * AD + col];
        uint4 pk;
        pk.x = pack2bf_manual(v[0], v[1]); pk.y = pack2bf_manual(v[2], v[3]);
        pk.z = pack2bf_manual(v[4], v[5]); pk.w = pack2bf_manual(v[6], v[7]);
        *(uint4*)(WL + cidx * 8) = pk;
    }
}

// ---------- kernel B: fused conv + pm + ploc + p + ctx partials ----------
// grid (63, 64); block 256 (4 waves). t-tile = 32.
__global__ __launch_bounds__(256, 4) void energy_kernel(
    const float* __restrict__ memory, const float* __restrict__ awcat,
    const float* __restrict__ Wconv, const float* __restrict__ Wv,
    const float* __restrict__ pq, const unsigned short* __restrict__ WB,
    const unsigned short* __restrict__ WL, float* __restrict__ wts,
    float* __restrict__ ctile, float* __restrict__ mloc,
    float* __restrict__ Stile) {
    const int tile = blockIdx.x;
    const int b = blockIdx.y;
    const int t0 = tile * 32;
    const int tid = threadIdx.x;

    __shared__ __align__(16) unsigned short Atile[32 * (ASTRIDE / 2)]; // bf16, swizzled
    __shared__ float aw_sm[2][64];
    __shared__ __align__(16) unsigned short conv_sm[32 * 40]; // row stride 40 bf16
    __shared__ float e_part[32][4];
    __shared__ float p_sm[32];

    // ---- stage phase 1: issue ALL 16 global loads up front
    float4 v[16];
    {
        const float4* msrc = (const float4*)(memory + ((size_t)b * T_SZ + t0) * MD);
        const bool full = (t0 + 32 <= T_SZ);
        if (full) {
            #pragma unroll
            for (int it = 0; it < 8; ++it) {
                int cid = it * 256 + tid;
                int r = cid >> 6, cc = cid & 63;
                v[2 * it]     = msrc[r * 128 + cc * 2];
                v[2 * it + 1] = msrc[r * 128 + cc * 2 + 1];
            }
        } else {
            #pragma unroll
            for (int it = 0; it < 8; ++it) {
                int cid = it * 256 + tid;
                int r = cid >> 6, cc = cid & 63;
                float4 z = {0, 0, 0, 0};
                bool ok = (t0 + r < T_SZ);
                v[2 * it]     = ok ? msrc[r * 128 + cc * 2]     : z;
                v[2 * it + 1] = ok ? msrc[r * 128 + cc * 2 + 1] : z;
            }
        }
    }

    // awc slice: indices i=0..62 -> t = t0-15+i  (zero pad OOB)
    if (tid < 128) {
        int c = tid >> 6, i = tid & 63;
        float val = 0.0f;
        int tv = t0 - 15 + i;
        if (i < 63 && tv >= 0 && tv < T_SZ) val = awcat[(b * 2 + c) * T_SZ + tv];
        aw_sm[c][i] = val;
    }

    // ---- stage phase 2: convert + LDS write (swizzled)
    {
        #pragma unroll
        for (int it = 0; it < 8; ++it) {
            int cid = it * 256 + tid;
            int r = cid >> 6, cc = cid & 63;
            float4 v0 = v[2 * it], v1 = v[2 * it + 1];
            uint4 pk;
            pk.x = pack2bf(v0.x, v0.y); pk.y = pack2bf(v0.z, v0.w);
            pk.z = pack2bf(v1.x, v1.y); pk.w = pack2bf(v1.z, v1.w);
            int off = r * ASTRIDE + ((cc * 16) ^ ((r & 7) << 4));
            *(uint4*)((char*)Atile + off) = pk;
        }
    }
    __syncthreads();

    // conv1d: thread = (f = tid&31, tq = tid>>5); 4 t's per thread
    {
        int f = tid & 31, tq = tid >> 5;
        float acc[4] = {0, 0, 0, 0};
        for (int k = 0; k < KW; ++k) {
            #pragma unroll
            for (int c = 0; c < 2; ++c) {
                float wv = Wconv[(k * 2 + c) * NF + f];
                #pragma unroll
                for (int tt = 0; tt < 4; ++tt)
                    acc[tt] += wv * aw_sm[c][tq + tt * 8 + k];
            }
        }
        #pragma unroll
        for (int tt = 0; tt < 4; ++tt)
            conv_sm[(tq + tt * 8) * 40 + f] = f2bf(acc[tt]);
    }
    __syncthreads();

    // MFMA phase
    const int w = tid >> 6, l = tid & 63;
    const int lr = l & 15, lg = l >> 4;
    const int d0 = (2 * w + 0) * 16 + lr;
    const int d1 = (2 * w + 1) * 16 + lr;
    const float pqv0 = pq[b * AD + d0], pqv1 = pq[b * AD + d1];
    const float wvv0 = Wv[d0], wvv1 = Wv[d1];

    f32x4 zero4 = {0, 0, 0, 0};
    f32x4 p00 = zero4, p01 = zero4, p10 = zero4, p11 = zero4;

    const s16x8* wbp = (const s16x8*)WB;
    const int swz = (lr & 7) << 4;
    const int rbase0 = lr * ASTRIDE;          // mtile 0 row byte base
    const int rbase1 = (16 + lr) * ASTRIDE;   // mtile 1
    const int inb = lg * 16;

    #pragma unroll
    for (int s = 0; s < 16; ++s) {
        int j = (inb + s * 64) ^ swz;
        s16x8 a0 = *(const s16x8*)((const char*)Atile + rbase0 + j);
        s16x8 a1 = *(const s16x8*)((const char*)Atile + rbase1 + j);
        s16x8 b0 = wbp[((2 * w + 0) * 16 + s) * 64 + l];
        s16x8 b1 = wbp[((2 * w + 1) * 16 + s) * 64 + l];
        p00 = __builtin_amdgcn_mfma_f32_16x16x32_bf16(a0, b0, p00, 0, 0, 0);
        p01 = __builtin_amdgcn_mfma_f32_16x16x32_bf16(a0, b1, p01, 0, 0, 0);
        p10 = __builtin_amdgcn_mfma_f32_16x16x32_bf16(a1, b0, p10, 0, 0, 0);
        p11 = __builtin_amdgcn_mfma_f32_16x16x32_bf16(a1, b1, p11, 0, 0, 0);
    }

    // ploc MFMA (K=32, one step)
    s16x8 la0 = *(const s16x8*)((const char*)conv_sm + (lr * 80 + lg * 16));
    s16x8 la1 = *(const s16x8*)((const char*)conv_sm + ((16 + lr) * 80 + lg * 16));
    const s16x8* wlp = (const s16x8*)WL;
    s16x8 lb0 = wlp[(2 * w + 0) * 64 + l];
    s16x8 lb1 = wlp[(2 * w + 1) * 64 + l];
    f32x4 q00 = __builtin_amdgcn_mfma_f32_16x16x32_bf16(la0, lb0, zero4, 0, 0, 0);
    f32x4 q01 = __builtin_amdgcn_mfma_f32_16x16x32_bf16(la0, lb1, zero4, 0, 0, 0);
    f32x4 q10 = __builtin_amdgcn_mfma_f32_16x16x32_bf16(la1, lb0, zero4, 0, 0, 0);
    f32x4 q11 = __builtin_amdgcn_mfma_f32_16x16x32_bf16(la1, lb1, zero4, 0, 0, 0);

    // epilogue: e[t] partial = sum_d tanh(pq + tanh(ploc) + tanh(pm)) * Wv
    float vr[8];
    #pragma unroll
    for (int r = 0; r < 4; ++r) {
        vr[r]     = fast_tanh(pqv0 + fast_tanh(q00[r]) + fast_tanh(p00[r])) * wvv0
                  + fast_tanh(pqv1 + fast_tanh(q01[r]) + fast_tanh(p01[r])) * wvv1;
        vr[4 + r] = fast_tanh(pqv0 + fast_tanh(q10[r]) + fast_tanh(p10[r])) * wvv0
                  + fast_tanh(pqv1 + fast_tanh(q11[r]) + fast_tanh(p11[r])) * wvv1;
    }
    #pragma unroll
    for (int j = 0; j < 8; ++j) {
        float vv = vr[j];
        vv += __shfl_xor(vv, 1);
        vv += __shfl_xor(vv, 2);
        vv += __shfl_xor(vv, 4);
        vv += __shfl_xor(vv, 8);
        if (lr == 0) e_part[(j >> 2) * 16 + lg * 4 + (j & 3)][w] = vv;
    }
    __syncthreads();

    if (tid < 32) {
        int t = t0 + tid;
        bool valid = t < T_SZ;
        float e = (e_part[tid][0] + e_part[tid][1]) + (e_part[tid][2] + e_part[tid][3]);
        float m = valid ? e : -3.4e38f;
        m = fmaxf(m, __shfl_xor(m, 1));
        m = fmaxf(m, __shfl_xor(m, 2));
        m = fmaxf(m, __shfl_xor(m, 4));
        m = fmaxf(m, __shfl_xor(m, 8));
        m = fmaxf(m, __shfl_xor(m, 16));
        float p = valid ? __expf(e - m) : 0.0f;
        p_sm[tid] = p;
        float S = p;
        S += __shfl_xor(S, 1);
        S += __shfl_xor(S, 2);
        S += __shfl_xor(S, 4);
        S += __shfl_xor(S, 8);
        S += __shfl_xor(S, 16);
        if (valid) wts[b * T_SZ + t] = p;
        if (tid == 0) { mloc[b * NTILE + tile] = m; Stile[b * NTILE + tile] = S; }
    }
    __syncthreads();

    // ctx partial: thread owns d = 2*tid, 2*tid+1
    {
        float c0 = 0.0f, c1 = 0.0f;
        const int boff = tid * 4;
        #pragma unroll
        for (int t = 0; t < 32; ++t) {
            float p = p_sm[t];
            unsigned int pk = *(const unsigned int*)(
                (const char*)Atile + t * ASTRIDE + (boff ^ ((t & 7) << 4)));
            c0 += p * __uint_as_float(pk << 16);
            c1 += p * __uint_as_float(pk & 0xffff0000u);
        }
        float2 o; o.x = c0; o.y = c1;
        ((float2*)ctile)[((b * NTILE + tile) << 8) + tid] = o;
    }
}

// ---------- kernel C: finalize (global M,Z; rescale wts; reduce ctx) ----------
// grid (64, 2); block 256. h = m-dim half.
__global__ __launch_bounds__(256) void finalize_kernel(
    const float* __restrict__ mloc, const float* __restrict__ Stile,
    const float* __restrict__ ctile, float* __restrict__ wts,
    float* __restrict__ ctx) {
    const int b = blockIdx.x, h = blockIdx.y, tid = threadIdx.x;
    __shared__ float sc_sm[NTILE + 1];
    if (tid < 64) {
        float m = (tid < NTILE) ? mloc[b * NTILE + tid] : -3.4e38f;
        float s = (tid < NTILE) ? Stile[b * NTILE + tid] : 0.0f;
        float M = m;
        M = fmaxf(M, __shfl_xor(M, 1));  M = fmaxf(M, __shfl_xor(M, 2));
        M = fmaxf(M, __shfl_xor(M, 4));  M = fmaxf(M, __shfl_xor(M, 8));
        M = fmaxf(M, __shfl_xor(M, 16)); M = fmaxf(M, __shfl_xor(M, 32));
        float e = __expf(m - M);
        float z = e * s;
        z += __shfl_xor(z, 1);  z += __shfl_xor(z, 2);
        z += __shfl_xor(z, 4);  z += __shfl_xor(z, 8);
        z += __shfl_xor(z, 16); z += __shfl_xor(z, 32);
        if (tid < NTILE) sc_sm[tid] = e / z;
    }
    __syncthreads();

    if (h == 0) {
        #pragma unroll
        for (int i = 0; i < 8; ++i) {
            int idx = tid + i * 256;
            if (idx < T_SZ) wts[b * T_SZ + idx] *= sc_sm[idx >> 5];
        }
    }

    float a = 0.0f;
    const float* cb = ctile + ((size_t)b * NTILE << 9) + h * 256 + tid;
    #pragma unroll 7
    for (int tl = 0; tl < NTILE; ++tl) a += sc_sm[tl] * cb[(size_t)tl << 9];
    ctx[b * MD + h * 256 + tid] = a;
}

// ---------- launch ----------
extern "C" void kernel_launch(void* const* d_in, const int* in_sizes, int n_in,
                              void* d_out, int out_size, void* d_ws, size_t ws_size,
                              hipStream_t stream) {
    const float* ahs    = (const float*)d_in[0];
    const float* memory = (const float*)d_in[1];
    const float* awcat  = (const float*)d_in[2];
    const float* Wq     = (const float*)d_in[3];
    const float* Wm     = (const float*)d_in[4];
    const float* Wv     = (const float*)d_in[5];
    const float* Wconv  = (const float*)d_in[6];
    const float* Wl     = (const float*)d_in[7];

    float* out = (float*)d_out;
    float* ctx = out;                 // [64][512]
    float* wts = out + B_SZ * MD;     // [64][2000]

    char* ws = (char*)d_ws;
    float* pq             = (float*)(ws);                    // 32 KB
    unsigned short* WB    = (unsigned short*)(ws + 32768);   // 128 KB
    unsigned short* WL    = (unsigned short*)(ws + 163840);  // 8 KB
    float* mloc           = (float*)(ws + 172032);           // 15.75 KB
    float* Stile          = (float*)(ws + 188160);           // 15.75 KB
    float* ctile          = (float*)(ws + 204800);           // 8.25 MB

    prep_kernel<<<81, 512, 0, stream>>>(ahs, Wq, Wm, Wl, pq, WB, WL);
    energy_kernel<<<dim3(NTILE, B_SZ), 256, 0, stream>>>(
        memory, awcat, Wconv, Wv, pq, WB, WL, wts, ctile, mloc, Stile);
    finalize_kernel<<<dim3(B_SZ, 2), 256, 0, stream>>>(mloc, Stile, ctile, wts, ctx);
}